// Round 3
// baseline (295.526 us; speedup 1.0000x reference)
//
#include <hip/hip_runtime.h>
#include <hip/hip_cooperative_groups.h>

namespace cg = cooperative_groups;

// NCEAverage: out[b,k] = exp(dot(memory[idx'[b,k]], x[b]) / T) / Z
//   idx'[b,0] = y[b], idx'[b,k>0] = idx[b,k];  Z = mean(e) * OUTPUT_SIZE
// x (256,128) f32, y (256,) int, idx (256,4097) int, memory (1281167,128) f32
// out (256,4097) f32.

constexpr int       kB       = 256;
constexpr int       kKp1     = 4097;       // K+1
constexpr long long kOutRows = 1281167LL;
constexpr int       kThreads = 256;
constexpr float     kInvT    = 1.0f / 0.07f;

__device__ __forceinline__ float dot4(float4 a, float4 b) {
    return a.x * b.x + a.y * b.y + a.z * b.z + a.w * b.w;
}

// Single cooperative kernel:
//  phase 1: gather rows, dot with x[b], exp, write e, per-block partial sum
//  grid.sync()
//  phase 2: every block redundantly reduces all partials in a FIXED order
//           (bit-identical scale everywhere), rescales its own chunk (L2-hot)
__global__ __launch_bounds__(kThreads) void nce_fused(
    const float* __restrict__ x, const int* __restrict__ y,
    const int* __restrict__ idx, const float* __restrict__ memory,
    float* __restrict__ out, float* __restrict__ blksum, int chunksPerB)
{
    const int nBlocks = gridDim.x;
    const int b     = blockIdx.x / chunksPerB;
    const int chunk = blockIdx.x % chunksPerB;
    const int tid   = threadIdx.x;
    const int wave  = tid >> 6;
    const int lane  = tid & 63;
    const int dlane = lane & 31;               // covers d = 4*dlane..4*dlane+3
    const int g     = wave * 2 + (lane >> 5);  // 0..7 groups per block

    const float4  xv   = reinterpret_cast<const float4*>(x)[b * 32 + dlane];
    const float4* m4   = reinterpret_cast<const float4*>(memory);
    const int*    idxb = idx + (size_t)b * kKp1;
    float*        outb = out + (size_t)b * kKp1;
    const int     ypos = y[b];

    const int per = (kKp1 + chunksPerB - 1) / chunksPerB;
    const int k0  = chunk * per;
    const int k1  = (k0 + per < kKp1) ? (k0 + per) : kKp1;

    float acc = 0.0f;
    for (int kb = k0 + g * 4; kb < k1; kb += 32) {
        const int krem = k1 - kb;              // >= 1
        const int r0 = (kb == 0) ? ypos : idxb[kb];
        const int r1 = (krem > 1) ? idxb[kb + 1] : 0;
        const int r2 = (krem > 2) ? idxb[kb + 2] : 0;
        const int r3 = (krem > 3) ? idxb[kb + 3] : 0;
        // 4 independent 512B row gathers in flight
        const float4 a0 = m4[(size_t)r0 * 32 + dlane];
        const float4 a1 = m4[(size_t)r1 * 32 + dlane];
        const float4 a2 = m4[(size_t)r2 * 32 + dlane];
        const float4 a3 = m4[(size_t)r3 * 32 + dlane];
        float d0 = dot4(a0, xv), d1 = dot4(a1, xv);
        float d2 = dot4(a2, xv), d3 = dot4(a3, xv);
        #pragma unroll
        for (int m = 16; m >= 1; m >>= 1) {
            d0 += __shfl_xor(d0, m, 64);
            d1 += __shfl_xor(d1, m, 64);
            d2 += __shfl_xor(d2, m, 64);
            d3 += __shfl_xor(d3, m, 64);
        }
        if (dlane == 0) {
            const float e0 = __expf(d0 * kInvT);
            const float e1 = __expf(d1 * kInvT);
            const float e2 = __expf(d2 * kInvT);
            const float e3 = __expf(d3 * kInvT);
            outb[kb] = e0;  acc += e0;
            if (krem > 1) { outb[kb + 1] = e1; acc += e1; }
            if (krem > 2) { outb[kb + 2] = e2; acc += e2; }
            if (krem > 3) { outb[kb + 3] = e3; acc += e3; }
        }
    }

    // block partial sum -> blksum[blockIdx.x]
    #pragma unroll
    for (int m = 32; m >= 1; m >>= 1)
        acc += __shfl_xor(acc, m, 64);
    __shared__ float red[kThreads / 64];
    if (lane == 0) red[wave] = acc;
    __syncthreads();
    if (tid == 0) {
        blksum[blockIdx.x] = red[0] + red[1] + red[2] + red[3];
        __threadfence();   // device-scope visibility before grid sync
    }

    cg::this_grid().sync();

    // phase 2: redundant fixed-order reduce -> identical scale in every block
    float s = 0.0f;
    for (int i = tid; i < nBlocks; i += kThreads) s += blksum[i];
    #pragma unroll
    for (int m = 32; m >= 1; m >>= 1)
        s += __shfl_xor(s, m, 64);
    __shared__ float red2[kThreads / 64];
    if (lane == 0) red2[wave] = s;
    __syncthreads();
    const float tot = red2[0] + red2[1] + red2[2] + red2[3];
    // out = e / Z, Z = tot / (B*(K+1)) * OUT_ROWS
    const float sc = ((float)(kB * kKp1) / (float)kOutRows) / tot;

    // rescale own chunk (just written by this block -> same-XCD L2 hit)
    for (int k = k0 + tid; k < k1; k += kThreads)
        outb[k] *= sc;
}

extern "C" void kernel_launch(void* const* d_in, const int* in_sizes, int n_in,
                              void* d_out, int out_size, void* d_ws, size_t ws_size,
                              hipStream_t stream) {
    const float* x      = (const float*)d_in[0];
    const int*   y      = (const int*)d_in[1];
    const int*   idx    = (const int*)d_in[2];
    const float* memory = (const float*)d_in[3];
    float*       out    = (float*)d_out;
    float*       blksum = (float*)d_ws;

    // size the cooperative grid to guaranteed co-residency
    int maxPerCU = 0;
    (void)hipOccupancyMaxActiveBlocksPerMultiprocessor(
        &maxPerCU, (const void*)nce_fused, kThreads, 0);
    if (maxPerCU < 1) maxPerCU = 1;
    int chunksPerB = (maxPerCU * 256) / kB;          // 256 CUs
    if (chunksPerB > 8) chunksPerB = 8;              // 2048 blocks max (full residency)
    if (chunksPerB < 1) chunksPerB = 1;
    const int nBlocks = kB * chunksPerB;

    void* args[] = { (void*)&x, (void*)&y, (void*)&idx, (void*)&memory,
                     (void*)&out, (void*)&blksum, (void*)&chunksPerB };
    (void)hipLaunchCooperativeKernel((const void*)nce_fused, dim3(nBlocks),
                                     dim3(kThreads), args, 0, stream);
}

// Round 4
// 93.092 us; speedup vs baseline: 3.1746x; 3.1746x over previous
//
#include <hip/hip_runtime.h>

// NCEAverage: out[b,k] = exp(dot(memory[idx'[b,k]], x[b]) / T) / Z
//   idx'[b,0] = y[b], idx'[b,k>0] = idx[b,k];  Z = mean(e) * OUTPUT_SIZE
// x (256,128) f32, y (256,) int, idx (256,4097) int, memory (1281167,128) f32
// out (256,4097) f32.

constexpr int       kB          = 256;
constexpr int       kKp1        = 4097;          // K+1 = 8*512 + 1
constexpr long long kOutRows    = 1281167LL;
constexpr int       kSplits     = 8;             // chunks per batch row (512 each)
constexpr int       kMainBlocks = kB * kSplits;  // 2048 = full residency
constexpr int       kThreads    = 256;
constexpr float     kInvT       = 1.0f / 0.07f;

__device__ __forceinline__ float dot4(float4 a, float4 b) {
    return a.x * b.x + a.y * b.y + a.z * b.z + a.w * b.w;
}

// kernel 1: gather rows, dot with x[b], exp, write e; per-block partial sum.
// Each 32-lane group owns 4 consecutive k per iteration (4 gathers in flight),
// with next-iteration indices prefetched during the gather wait.
__global__ __launch_bounds__(kThreads) void nce_main(
    const float* __restrict__ x, const int* __restrict__ y,
    const int* __restrict__ idx, const float* __restrict__ memory,
    float* __restrict__ out, float* __restrict__ blksum)
{
    const int b     = blockIdx.x >> 3;
    const int chunk = blockIdx.x & 7;
    const int tid   = threadIdx.x;
    const int wave  = tid >> 6;
    const int lane  = tid & 63;
    const int dlane = lane & 31;               // covers d = 4*dlane..4*dlane+3
    const int g     = wave * 2 + (lane >> 5);  // 0..7 groups per block

    const float4  xv   = reinterpret_cast<const float4*>(x)[b * 32 + dlane];
    const float4* m4   = reinterpret_cast<const float4*>(memory);
    const int*    idxb = idx + (size_t)b * kKp1;
    float*        outb = out + (size_t)b * kKp1;

    const int k0 = chunk * 512;
    const int k1 = (chunk == 7) ? kKp1 : k0 + 512;   // last chunk gets 513

    float acc = 0.0f;
    int kb = k0 + g * 4;

    // steady state: full 4-row iterations with index prefetch
    if (kb + 4 <= k1) {
        int r0 = (kb == 0) ? y[b] : idxb[kb];
        int r1 = idxb[kb + 1], r2 = idxb[kb + 2], r3 = idxb[kb + 3];
        while (true) {
            // 4 independent 512B row gathers in flight
            const float4 a0 = m4[(size_t)r0 * 32 + dlane];
            const float4 a1 = m4[(size_t)r1 * 32 + dlane];
            const float4 a2 = m4[(size_t)r2 * 32 + dlane];
            const float4 a3 = m4[(size_t)r3 * 32 + dlane];

            // prefetch next iteration's indices while gathers are in flight
            const int knext = kb + 32;
            const bool more = (knext + 4 <= k1);
            int s0, s1, s2, s3;
            if (more) {
                s0 = idxb[knext];     s1 = idxb[knext + 1];
                s2 = idxb[knext + 2]; s3 = idxb[knext + 3];
            }

            float d0 = dot4(a0, xv), d1 = dot4(a1, xv);
            float d2 = dot4(a2, xv), d3 = dot4(a3, xv);
            #pragma unroll
            for (int m = 16; m >= 1; m >>= 1) {
                d0 += __shfl_xor(d0, m, 64);
                d1 += __shfl_xor(d1, m, 64);
                d2 += __shfl_xor(d2, m, 64);
                d3 += __shfl_xor(d3, m, 64);
            }
            if (dlane == 0) {
                const float e0 = __expf(d0 * kInvT);
                const float e1 = __expf(d1 * kInvT);
                const float e2 = __expf(d2 * kInvT);
                const float e3 = __expf(d3 * kInvT);
                outb[kb]     = e0;  acc += e0;
                outb[kb + 1] = e1;  acc += e1;
                outb[kb + 2] = e2;  acc += e2;
                outb[kb + 3] = e3;  acc += e3;
            }
            if (!more) { kb = knext; break; }
            kb = knext;
            r0 = s0; r1 = s1; r2 = s2; r3 = s3;
        }
    }

    // tail (only chunk 7, group 0: k = 4096) — k > 0 guaranteed here
    for (int k = kb; k < k1; ++k) {
        const int row = idxb[k];
        const float4 a = m4[(size_t)row * 32 + dlane];
        float d = dot4(a, xv);
        #pragma unroll
        for (int m = 16; m >= 1; m >>= 1)
            d += __shfl_xor(d, m, 64);
        if (dlane == 0) {
            const float e = __expf(d * kInvT);
            outb[k] = e;  acc += e;
        }
    }

    // block partial sum -> blksum[blockIdx.x]
    #pragma unroll
    for (int m = 32; m >= 1; m >>= 1)
        acc += __shfl_xor(acc, m, 64);
    __shared__ float red[kThreads / 64];
    if (lane == 0) red[wave] = acc;
    __syncthreads();
    if (tid == 0)
        blksum[blockIdx.x] = red[0] + red[1] + red[2] + red[3];
}

// kernel 2: every block redundantly reduces the 2048 partials (fixed order ->
// bit-identical scale in all blocks), then scales its chunk of out.
__global__ __launch_bounds__(256) void nce_norm(
    float4* __restrict__ out4, const float* __restrict__ blksum, int n4)
{
    float s = 0.0f;
    for (int i = threadIdx.x; i < kMainBlocks; i += 256) s += blksum[i];
    #pragma unroll
    for (int m = 32; m >= 1; m >>= 1)
        s += __shfl_xor(s, m, 64);
    __shared__ float red[4];
    if ((threadIdx.x & 63) == 0) red[threadIdx.x >> 6] = s;
    __syncthreads();
    const float tot = red[0] + red[1] + red[2] + red[3];
    // out = e / Z, Z = tot / (B*(K+1)) * OUT_ROWS
    const float sc = ((float)(kB * kKp1) / (float)kOutRows) / tot;

    int i = blockIdx.x * blockDim.x + threadIdx.x;
    const int stride = gridDim.x * blockDim.x;
    for (; i < n4; i += stride) {
        float4 v = out4[i];
        v.x *= sc; v.y *= sc; v.z *= sc; v.w *= sc;
        out4[i] = v;
    }
}

extern "C" void kernel_launch(void* const* d_in, const int* in_sizes, int n_in,
                              void* d_out, int out_size, void* d_ws, size_t ws_size,
                              hipStream_t stream) {
    const float* x      = (const float*)d_in[0];
    const int*   y      = (const int*)d_in[1];
    const int*   idx    = (const int*)d_in[2];
    const float* memory = (const float*)d_in[3];
    float*       out    = (float*)d_out;
    float*       blksum = (float*)d_ws;   // kMainBlocks partials

    hipLaunchKernelGGL(nce_main, dim3(kMainBlocks), dim3(kThreads), 0, stream,
                       x, y, idx, memory, out, blksum);
    hipLaunchKernelGGL(nce_norm, dim3(1024), dim3(256), 0, stream,
                       (float4*)d_out, blksum, out_size / 4);
}

// Round 5
// 91.830 us; speedup vs baseline: 3.2182x; 1.0137x over previous
//
#include <hip/hip_runtime.h>

// NCEAverage: out[b,k] = exp(dot(memory[idx'[b,k]], x[b]) / T) / Z
//   idx'[b,0] = y[b], idx'[b,k>0] = idx[b,k];  Z = mean(e) * OUTPUT_SIZE
// x (256,128) f32, y (256,) int, idx (256,4097) int, memory (1281167,128) f32
// out (256,4097) f32.

constexpr int       kB          = 256;
constexpr int       kKp1        = 4097;          // K+1 = 8*512 + 1
constexpr long long kOutRows    = 1281167LL;
constexpr int       kSplits     = 8;             // chunks per batch row (512 each)
constexpr int       kMainBlocks = kB * kSplits;  // 2048 = full residency
constexpr int       kThreads    = 256;
constexpr float     kInvT       = 1.0f / 0.07f;

__device__ __forceinline__ float dot4(float4 a, float4 b) {
    return a.x * b.x + a.y * b.y + a.z * b.z + a.w * b.w;
}

// kernel 1: each 32-lane group owns 8 consecutive k per iteration:
// 8 independent 512B row gathers in flight, then a multi-accumulator tree
// reduce (9 shuffles for all 8 row-sums) with results on distinct lanes ->
// one coalesced 8-lane store + single 8-active-lane exp.
__global__ __launch_bounds__(kThreads) void nce_main(
    const float* __restrict__ x, const int* __restrict__ y,
    const int* __restrict__ idx, const float* __restrict__ memory,
    float* __restrict__ out, float* __restrict__ blksum)
{
    const int b     = blockIdx.x >> 3;
    const int chunk = blockIdx.x & 7;
    const int tid   = threadIdx.x;
    const int wave  = tid >> 6;
    const int lane  = tid & 63;
    const int dlane = lane & 31;               // covers d = 4*dlane..4*dlane+3
    const int g     = wave * 2 + (lane >> 5);  // 0..7 groups per block

    const float4  xv   = reinterpret_cast<const float4*>(x)[b * 32 + dlane];
    const float4* m4   = reinterpret_cast<const float4*>(memory);
    const int*    idxb = idx + (size_t)b * kKp1;
    float*        outb = out + (size_t)b * kKp1;
    const int     ypos = y[b];

    const int k0 = chunk * 512;
    float acc = 0.0f;

    // lane that stores row kb+j: lanes with (dlane&3)==0, j = 4*b2+2*b3+b4
    const bool storer = (dlane & 3) == 0;
    const int  jmap   = ((dlane >> 2) & 1) * 4 + ((dlane >> 3) & 1) * 2 +
                        ((dlane >> 4) & 1);

    int kb = k0 + g * 8;
    #pragma unroll 1
    for (int it = 0; it < 8; ++it, kb += 64) {
        // 8 row indices (uniform within the group; 4B-aligned scalar loads)
        const int r0 = (kb == 0) ? ypos : idxb[kb];
        const int r1 = idxb[kb + 1], r2 = idxb[kb + 2], r3 = idxb[kb + 3];
        const int r4 = idxb[kb + 4], r5 = idxb[kb + 5];
        const int r6 = idxb[kb + 6], r7 = idxb[kb + 7];

        // 8 independent 512B row gathers in flight
        const float4 a0 = m4[(size_t)r0 * 32 + dlane];
        const float4 a1 = m4[(size_t)r1 * 32 + dlane];
        const float4 a2 = m4[(size_t)r2 * 32 + dlane];
        const float4 a3 = m4[(size_t)r3 * 32 + dlane];
        const float4 a4 = m4[(size_t)r4 * 32 + dlane];
        const float4 a5 = m4[(size_t)r5 * 32 + dlane];
        const float4 a6 = m4[(size_t)r6 * 32 + dlane];
        const float4 a7 = m4[(size_t)r7 * 32 + dlane];

        const float d0 = dot4(a0, xv), d1 = dot4(a1, xv);
        const float d2 = dot4(a2, xv), d3 = dot4(a3, xv);
        const float d4 = dot4(a4, xv), d5 = dot4(a5, xv);
        const float d6 = dot4(a6, xv), d7 = dot4(a7, xv);

        // multi-accumulator butterfly: 9 shuffles reduce all 8 rows.
        // stage xor-16: pair-combine {0,1},{2,3},{4,5},{6,7}
        const bool h16 = (dlane & 16) != 0;
        float r01 = (h16 ? d1 : d0) + __shfl_xor(h16 ? d0 : d1, 16, 64);
        float r23 = (h16 ? d3 : d2) + __shfl_xor(h16 ? d2 : d3, 16, 64);
        float r45 = (h16 ? d5 : d4) + __shfl_xor(h16 ? d4 : d5, 16, 64);
        float r67 = (h16 ? d7 : d6) + __shfl_xor(h16 ? d6 : d7, 16, 64);
        // stage xor-8: pair-combine {01,23},{45,67}
        const bool h8 = (dlane & 8) != 0;
        float r03 = (h8 ? r23 : r01) + __shfl_xor(h8 ? r01 : r23, 8, 64);
        float r47 = (h8 ? r67 : r45) + __shfl_xor(h8 ? r45 : r67, 8, 64);
        // stage xor-4: pair-combine {0123,4567}
        const bool h4 = (dlane & 4) != 0;
        float r = (h4 ? r47 : r03) + __shfl_xor(h4 ? r03 : r47, 4, 64);
        // finish within the 4-lane slot
        r += __shfl_xor(r, 2, 64);
        r += __shfl_xor(r, 1, 64);
        // lane l now holds full sum for row j = 4*b2+2*b3+b4 (b_i = bit i of l)

        const float e = __expf(r * kInvT);
        if (storer) {                 // 8 lanes, contiguous 32B store segment
            outb[kb + jmap] = e;
            acc += e;
        }
    }

    // tail: k = 4096 (chunk 7 only; handled by group 0)
    if (chunk == 7 && g == 0) {
        const int row = idxb[4096];
        const float4 a = m4[(size_t)row * 32 + dlane];
        float d = dot4(a, xv);
        #pragma unroll
        for (int m = 16; m >= 1; m >>= 1)
            d += __shfl_xor(d, m, 64);
        if (dlane == 0) {
            const float e = __expf(d * kInvT);
            outb[4096] = e;  acc += e;
        }
    }

    // block partial sum -> blksum[blockIdx.x]
    #pragma unroll
    for (int m = 32; m >= 1; m >>= 1)
        acc += __shfl_xor(acc, m, 64);
    __shared__ float red[kThreads / 64];
    if (lane == 0) red[wave] = acc;
    __syncthreads();
    if (tid == 0)
        blksum[blockIdx.x] = red[0] + red[1] + red[2] + red[3];
}

// kernel 2: every block redundantly reduces the 2048 partials (fixed order ->
// bit-identical scale in all blocks), then scales its chunk of out.
__global__ __launch_bounds__(256) void nce_norm(
    float4* __restrict__ out4, const float* __restrict__ blksum, int n4)
{
    float s = 0.0f;
    for (int i = threadIdx.x; i < kMainBlocks; i += 256) s += blksum[i];
    #pragma unroll
    for (int m = 32; m >= 1; m >>= 1)
        s += __shfl_xor(s, m, 64);
    __shared__ float red[4];
    if ((threadIdx.x & 63) == 0) red[threadIdx.x >> 6] = s;
    __syncthreads();
    const float tot = red[0] + red[1] + red[2] + red[3];
    // out = e / Z, Z = tot / (B*(K+1)) * OUT_ROWS
    const float sc = ((float)(kB * kKp1) / (float)kOutRows) / tot;

    int i = blockIdx.x * blockDim.x + threadIdx.x;
    const int stride = gridDim.x * blockDim.x;
    for (; i < n4; i += stride) {
        float4 v = out4[i];
        v.x *= sc; v.y *= sc; v.z *= sc; v.w *= sc;
        out4[i] = v;
    }
}

extern "C" void kernel_launch(void* const* d_in, const int* in_sizes, int n_in,
                              void* d_out, int out_size, void* d_ws, size_t ws_size,
                              hipStream_t stream) {
    const float* x      = (const float*)d_in[0];
    const int*   y      = (const int*)d_in[1];
    const int*   idx    = (const int*)d_in[2];
    const float* memory = (const float*)d_in[3];
    float*       out    = (float*)d_out;
    float*       blksum = (float*)d_ws;   // kMainBlocks partials

    hipLaunchKernelGGL(nce_main, dim3(kMainBlocks), dim3(kThreads), 0, stream,
                       x, y, idx, memory, out, blksum);
    hipLaunchKernelGGL(nce_norm, dim3(1024), dim3(256), 0, stream,
                       (float4*)d_out, blksum, out_size / 4);
}